// Round 3
// baseline (792.868 us; speedup 1.0000x reference)
//
#include <hip/hip_runtime.h>
#include <stdint.h>

#define N_TOK    8192
#define DM       1024      // D_MODEL
#define DE       4096      // D_EXPERT
#define NEXP     8
#define CAP      2560
#define AUX_CO   0.01f
#define Z_CO     0.001f

typedef __attribute__((ext_vector_type(4))) float f32x4;
typedef __attribute__((ext_vector_type(8))) __bf16 bf16x8;

static __device__ __forceinline__ unsigned short f2bf(float f) {
  union { float f; uint32_t u; } v; v.f = f;
  uint32_t r = 0x7fffu + ((v.u >> 16) & 1u);
  return (unsigned short)((v.u + r) >> 16);
}
static __device__ __forceinline__ float bf2f(unsigned short u) {
  union { uint32_t u; float f; } v; v.u = ((uint32_t)u) << 16;
  return v.f;
}

#define MEMFENCE() asm volatile("" ::: "memory")
#define BAR()    do { MEMFENCE(); __builtin_amdgcn_s_barrier(); MEMFENCE(); } while (0)
#define LGKM0()  asm volatile("s_waitcnt lgkmcnt(0)" ::: "memory")
#define VMW(N)   asm volatile("s_waitcnt vmcnt(" #N ")" ::: "memory")
#define SB0()    __builtin_amdgcn_sched_barrier(0)

// ---------------- init: inv map = -1 ----------------
__global__ void init_inv(int* __restrict__ inv) {
  int i = blockIdx.x * 256 + threadIdx.x;
  if (i < NEXP * CAP) inv[i] = -1;
}

// ---------------- transpose + fp32->bf16: in (R,C) -> out (C,R), per expert z ----------------
__global__ __launch_bounds__(256) void transpose_to_bf16(
    const float* __restrict__ in, unsigned short* __restrict__ out, int R, int C)
{
  __shared__ float tile[32][33];
  const size_t eoff = (size_t)blockIdx.z * R * C;
  const int bx = blockIdx.x * 32, by = blockIdx.y * 32;
  const int tx = threadIdx.x & 31, ty = threadIdx.x >> 5;   // ty 0..7
#pragma unroll
  for (int i = 0; i < 4; ++i)
    tile[ty + 8*i][tx] = in[eoff + (size_t)(by + ty + 8*i) * C + bx + tx];
  __syncthreads();
#pragma unroll
  for (int i = 0; i < 4; ++i)
    out[eoff + (size_t)(bx + ty + 8*i) * R + by + tx] = f2bf(tile[tx][ty + 8*i]);
}

// ---------------- router ----------------
__global__ __launch_bounds__(256) void router_kernel(
    const float* __restrict__ x, const float* __restrict__ Wr,
    int* __restrict__ topk, float* __restrict__ tkw, float* __restrict__ zP)
{
  const int tid = threadIdx.x, lane = tid & 63, wave = tid >> 6;
  float zacc = 0.f;
  float pacc[NEXP];
#pragma unroll
  for (int e = 0; e < NEXP; ++e) pacc[e] = 0.f;

  for (int it = 0; it < 4; ++it) {
    const int t = blockIdx.x * 16 + it * 4 + wave;
    float acc[NEXP];
#pragma unroll
    for (int e = 0; e < NEXP; ++e) acc[e] = 0.f;
    const f32x4* x4 = (const f32x4*)(x + (size_t)t * DM);
#pragma unroll
    for (int i = 0; i < 4; ++i) {
      f32x4 xv = x4[i * 64 + lane];
#pragma unroll
      for (int j = 0; j < 4; ++j) {
        const float xs = xv[j];
        const float* wr = Wr + (size_t)((i * 64 + lane) * 4 + j) * NEXP;
#pragma unroll
        for (int e = 0; e < NEXP; ++e) acc[e] += xs * wr[e];
      }
    }
#pragma unroll
    for (int m = 32; m; m >>= 1)
#pragma unroll
      for (int e = 0; e < NEXP; ++e) acc[e] += __shfl_xor(acc[e], m);

    float mx = acc[0];
#pragma unroll
    for (int e = 1; e < NEXP; ++e) mx = fmaxf(mx, acc[e]);
    float p[NEXP], s = 0.f;
#pragma unroll
    for (int e = 0; e < NEXP; ++e) { p[e] = expf(acc[e] - mx); s += p[e]; }
    const float lse = mx + logf(s);
    zacc += lse * lse;
    const float inv_s = 1.f / s;
#pragma unroll
    for (int e = 0; e < NEXP; ++e) pacc[e] += p[e] * inv_s;

    int e0 = 0; float v0 = p[0];
#pragma unroll
    for (int e = 1; e < NEXP; ++e) if (p[e] > v0) { v0 = p[e]; e0 = e; }
    int e1 = -1; float v1 = -1.f;
#pragma unroll
    for (int e = 0; e < NEXP; ++e) if (e != e0 && p[e] > v1) { v1 = p[e]; e1 = e; }

    const float pr0 = v0 * inv_s, pr1 = v1 * inv_s;
    const float denom = fmaxf(pr0 + pr1, 1e-9f);
    if (lane == 0) {
      topk[2*t]   = e0; topk[2*t+1] = e1;
      tkw[2*t]    = pr0 / denom; tkw[2*t+1] = pr1 / denom;
    }
  }
  __shared__ float blk[4][9];
  if (lane == 0) {
    blk[wave][0] = zacc;
#pragma unroll
    for (int e = 0; e < NEXP; ++e) blk[wave][1 + e] = pacc[e];
  }
  __syncthreads();
  if (tid < 9)
    zP[blockIdx.x * 9 + tid] = blk[0][tid] + blk[1][tid] + blk[2][tid] + blk[3][tid];
}

// ---------------- scan: FCFS capacity positions, wave per expert ----------------
__global__ __launch_bounds__(512) void scan_kernel(
    const int2* __restrict__ topk, const float2* __restrict__ tkw,
    int* __restrict__ posk, float* __restrict__ wts,
    int* __restrict__ inv, int* __restrict__ kept)
{
  const int lane = threadIdx.x & 63;
  const int e = threadIdx.x >> 6;           // 8 waves = 8 experts
  int base = 0;
  const uint64_t below = (lane == 63) ? 0xFFFFFFFFFFFFFFFFull >> 1
                                      : ((1ull << lane) - 1ull);
  for (int i = 0; i < N_TOK / 64; ++i) {
    const int t = i * 64 + lane;
    const int2 ti = topk[t];
    const float2 w = tkw[t];
    const bool hit = (ti.x == e) || (ti.y == e);
    const uint64_t m = __ballot(hit);
    if (hit) {
      const int pos = base + (int)__popcll(m & below);
      const bool kp = pos < CAP;
      const int k = (ti.x == e) ? 0 : 1;
      posk[2*t + k] = kp ? pos : CAP;
      wts[2*t + k]  = kp ? ((k == 0) ? w.x : w.y) : 0.f;
      if (kp) inv[e * CAP + pos] = t;
    }
    base += (int)__popcll(m);
  }
  if (lane == 0) kept[e] = base < CAP ? base : CAP;
}

// ---------------- dispatch ----------------
__global__ __launch_bounds__(256) void dispatch_kernel(
    const float* __restrict__ x, const int* __restrict__ inv,
    unsigned short* __restrict__ buf)
{
  const int slot = blockIdx.x;
  const int t = inv[slot];
  ushort4 o;
  if (t >= 0) {
    const f32x4 v = ((const f32x4*)(x + (size_t)t * DM))[threadIdx.x];
    o.x = f2bf(v[0]); o.y = f2bf(v[1]); o.z = f2bf(v[2]); o.w = f2bf(v[3]);
  } else {
    o.x = 0; o.y = 0; o.z = 0; o.w = 0;
  }
  ((ushort4*)(buf + (size_t)slot * DM))[threadIdx.x] = o;
}

// ---------------- deep-pipelined grouped GEMM ----------------
// C[e](M,N) = A[e](M,K) x Bt[e](N,K)^T + bias; BN=256, BK=32, ring-4 LDS,
// prefetch distance 3, ONE barrier/slice, counted vmcnt (never 0 mid-loop).
template<int BM, bool RELU>
__global__ __launch_bounds__(512, 2) void gemm8p(
    const unsigned short* __restrict__ A,   // (E, M, K) bf16
    const unsigned short* __restrict__ Bt,  // (E, N, K) bf16
    const float* __restrict__ bias,         // (E, N)
    unsigned short* __restrict__ C,         // (E, M, N) bf16
    int M, int N, int K, int nwg)
{
  constexpr int MF  = BM / 32;          // m-frags per wave (8 or 4)
  constexpr int AI  = (BM * 64) / 8192; // A stage instrs per slice (2 or 1)
  constexpr int ASZ = BM * 32;          // A slice elems
  constexpr int BSZ = 256 * 32;         // B slice elems
  __shared__ __attribute__((aligned(16))) unsigned short As[4 * ASZ];
  __shared__ __attribute__((aligned(16))) unsigned short Bs[4 * BSZ];

  const int tid = threadIdx.x;
  const int lane = tid & 63, wave = tid >> 6;
  const int wr = wave >> 2, wc = wave & 3;
  const int frow = lane & 15, kgrp = lane >> 4;

  // bijective XCD swizzle (nwg % 8 == 0), n fastest within expert for L2 reuse
  int wg = (int)blockIdx.x;
  wg = (wg & 7) * (nwg >> 3) + (wg >> 3);
  const int nn = N >> 8;
  const int ntpe = (M / BM) * nn;
  const int e  = wg / ntpe;
  const int rr = wg % ntpe;
  const int m0 = (rr / nn) * BM;
  const int n0 = (rr % nn) * 256;
  const unsigned short* Ae = A  + (size_t)e * M * K + (size_t)m0 * K;
  const unsigned short* Be = Bt + (size_t)e * N * K + (size_t)n0 * K;

  auto stageA = [&](int s) {
    const int sl = s & 3, k0 = s * 32;
#pragma unroll
    for (int i = 0; i < AI; ++i) {
      const int row = i * 128 + (tid >> 2);
      const int col = ((tid & 3) ^ ((row >> 1) & 3)) * 8;
      const unsigned short* g = Ae + (size_t)row * K + (k0 + col);
      unsigned short* l = &As[sl * ASZ + i * 4096 + (tid & 448) * 8];
      __builtin_amdgcn_global_load_lds((const __attribute__((address_space(1))) void*)g,
                                       (__attribute__((address_space(3))) void*)l, 16, 0, 0);
    }
  };
  auto stageB = [&](int s) {
    const int sl = s & 3, k0 = s * 32;
#pragma unroll
    for (int i = 0; i < 2; ++i) {
      const int row = i * 128 + (tid >> 2);
      const int col = ((tid & 3) ^ ((row >> 1) & 3)) * 8;
      const unsigned short* g = Be + (size_t)row * K + (k0 + col);
      unsigned short* l = &Bs[sl * BSZ + i * 4096 + (tid & 448) * 8];
      __builtin_amdgcn_global_load_lds((const __attribute__((address_space(1))) void*)g,
                                       (__attribute__((address_space(3))) void*)l, 16, 0, 0);
    }
  };
  auto ldA = [&](int sl, int mf) -> bf16x8 {
    const int row = wr * (MF * 16) + mf * 16 + frow;
    return *(const bf16x8*)&As[sl * ASZ + row * 32 + ((kgrp ^ ((row >> 1) & 3)) * 8)];
  };
  auto ldB = [&](int sl, int nf) -> bf16x8 {
    const int row = wc * 64 + nf * 16 + frow;
    return *(const bf16x8*)&Bs[sl * BSZ + row * 32 + ((kgrp ^ ((row >> 1) & 3)) * 8)];
  };

  f32x4 acc[MF][4];
#pragma unroll
  for (int m = 0; m < MF; ++m)
#pragma unroll
    for (int n = 0; n < 4; ++n) acc[m][n] = (f32x4){0.f, 0.f, 0.f, 0.f};

  const int nk = K >> 5;   // >= 32 always here

  // prologue: slices 0,1,2 in flight; wait for slice 0 (leave 2 slices pending)
  stageA(0); stageB(0); stageA(1); stageB(1); stageA(2); stageB(2);
  if constexpr (AI == 2) VMW(8); else VMW(6);
  BAR();

  for (int s = 0; s < nk; ++s) {
    const int cur = s & 3;
    bf16x8 bq[4], afl[MF / 2], afh[MF / 2];
    // fragment reads for this slice (B + lower A), then prefetch slice s+3
#pragma unroll
    for (int nf = 0; nf < 4; ++nf) bq[nf] = ldB(cur, nf);
#pragma unroll
    for (int m = 0; m < MF / 2; ++m) afl[m] = ldA(cur, m);
    if (s + 3 < nk) { stageA(s + 3); stageB(s + 3); }
    LGKM0(); SB0();
    __builtin_amdgcn_s_setprio(1);
#pragma unroll
    for (int m = 0; m < MF / 2; ++m)
#pragma unroll
      for (int nf = 0; nf < 4; ++nf)
        acc[m][nf] = __builtin_amdgcn_mfma_f32_16x16x32_bf16(afl[m], bq[nf], acc[m][nf], 0, 0, 0);
    __builtin_amdgcn_s_setprio(0);
    // upper-A reads issue while lower MFMAs execute
#pragma unroll
    for (int m = 0; m < MF / 2; ++m) afh[m] = ldA(cur, MF / 2 + m);
    LGKM0(); SB0();
    __builtin_amdgcn_s_setprio(1);
#pragma unroll
    for (int m = 0; m < MF / 2; ++m)
#pragma unroll
      for (int nf = 0; nf < 4; ++nf)
        acc[MF / 2 + m][nf] = __builtin_amdgcn_mfma_f32_16x16x32_bf16(afh[m], bq[nf], acc[MF / 2 + m][nf], 0, 0, 0);
    __builtin_amdgcn_s_setprio(0);
    // slice boundary: counted vmcnt so next slice's data is ready; one barrier
    if (s + 1 < nk) {
      if (s + 3 < nk)      { if constexpr (AI == 2) VMW(8); else VMW(6); }
      else if (s + 2 < nk) { if constexpr (AI == 2) VMW(4); else VMW(3); }
      else                 VMW(0);
      BAR();
    }
  }

  // epilogue: D row = 4*kgrp + reg, col = frow (m89/m91 layout)
  const int r0 = m0 + wr * (MF * 16) + 4 * kgrp;
  const int c0 = n0 + wc * 64 + frow;
#pragma unroll
  for (int nf = 0; nf < 4; ++nf) {
    const int cc = c0 + nf * 16;
    const float bv = bias[(size_t)e * N + cc];
#pragma unroll
    for (int m = 0; m < MF; ++m) {
#pragma unroll
      for (int r = 0; r < 4; ++r) {
        float v = acc[m][nf][r] + bv;
        if (RELU) v = fmaxf(v, 0.f);
        C[((size_t)e * M + (r0 + m * 16 + r)) * N + cc] = f2bf(v);
      }
    }
  }
}

// ---------------- combine ----------------
__global__ __launch_bounds__(256) void combine_kernel(
    const unsigned short* __restrict__ eo, const int* __restrict__ posk,
    const float* __restrict__ wts, const int* __restrict__ topk,
    float* __restrict__ out)
{
  const int t = blockIdx.x;
  const int e0 = topk[2*t], e1 = topk[2*t+1];
  int p0 = posk[2*t], p1 = posk[2*t+1];
  p0 = p0 < CAP - 1 ? p0 : CAP - 1;
  p1 = p1 < CAP - 1 ? p1 : CAP - 1;
  const float w0 = wts[2*t], w1 = wts[2*t+1];
  const ushort4 a = ((const ushort4*)(eo + ((size_t)e0 * CAP + p0) * DM))[threadIdx.x];
  const ushort4 b = ((const ushort4*)(eo + ((size_t)e1 * CAP + p1) * DM))[threadIdx.x];
  f32x4 o;
  o[0] = w0 * bf2f(a.x) + w1 * bf2f(b.x);
  o[1] = w0 * bf2f(a.y) + w1 * bf2f(b.y);
  o[2] = w0 * bf2f(a.z) + w1 * bf2f(b.z);
  o[3] = w0 * bf2f(a.w) + w1 * bf2f(b.w);
  ((f32x4*)(out + (size_t)t * DM))[threadIdx.x] = o;
}

// ---------------- finalize scalars ----------------
__global__ __launch_bounds__(64) void finalize_kernel(
    const float* __restrict__ zP, const int* __restrict__ kept,
    float* __restrict__ outs)
{
  const int lane = threadIdx.x;
  float v[9];
#pragma unroll
  for (int e = 0; e < 9; ++e) {
    float s = 0.f;
    for (int b = 0; b < 8; ++b) s += zP[(lane * 8 + b) * 9 + e];
    v[e] = s;
  }
#pragma unroll
  for (int m = 32; m; m >>= 1)
#pragma unroll
    for (int e = 0; e < 9; ++e) v[e] += __shfl_xor(v[e], m);
  if (lane == 0) {
    const float z = v[0] / (float)N_TOK;
    float total = 0.f;
    for (int e = 0; e < NEXP; ++e) total += (float)kept[e];
    total = fmaxf(total, 1.f);
    float aux = 0.f;
    for (int e = 0; e < NEXP; ++e)
      aux += ((float)kept[e] / total) * (v[1 + e] / (float)N_TOK);
    aux *= (float)NEXP;
    outs[0] = aux;
    outs[1] = z;
    outs[2] = AUX_CO * aux + Z_CO * z;
  }
}

extern "C" void kernel_launch(void* const* d_in, const int* in_sizes, int n_in,
                              void* d_out, int out_size, void* d_ws, size_t ws_size,
                              hipStream_t stream)
{
  const float* x  = (const float*)d_in[0];
  const float* Wr = (const float*)d_in[1];
  const float* W1 = (const float*)d_in[2];
  const float* b1 = (const float*)d_in[3];
  const float* W2 = (const float*)d_in[4];
  const float* b2 = (const float*)d_in[5];
  float* out = (float*)d_out;

  char* p = (char*)d_ws;
  auto alloc = [&](size_t bytes) {
    char* q = p; p += (bytes + 255) & ~(size_t)255; return q;
  };
  unsigned short* W1t = (unsigned short*)alloc((size_t)NEXP * DM * DE * 2);   // (E, DE, DM)
  unsigned short* W2t = (unsigned short*)alloc((size_t)NEXP * DM * DE * 2);   // (E, DM, DE)
  unsigned short* buf = (unsigned short*)alloc((size_t)NEXP * CAP * DM * 2);  // (E, cap, DM)
  unsigned short* h   = (unsigned short*)alloc((size_t)NEXP * CAP * DE * 2);  // (E, cap, DE)
  unsigned short* eo  = (unsigned short*)alloc((size_t)NEXP * CAP * DM * 2);  // (E, cap, DM)
  int*   topk = (int*)alloc((size_t)N_TOK * 2 * 4);
  float* tkw  = (float*)alloc((size_t)N_TOK * 2 * 4);
  int*   posk = (int*)alloc((size_t)N_TOK * 2 * 4);
  float* wts  = (float*)alloc((size_t)N_TOK * 2 * 4);
  int*   inv  = (int*)alloc((size_t)NEXP * CAP * 4);
  int*   kept = (int*)alloc((size_t)NEXP * 4);
  float* zP   = (float*)alloc((size_t)512 * 9 * 4);

  init_inv<<<(NEXP * CAP + 255) / 256, 256, 0, stream>>>(inv);
  transpose_to_bf16<<<dim3(DE / 32, DM / 32, NEXP), 256, 0, stream>>>(W1, W1t, DM, DE);
  transpose_to_bf16<<<dim3(DM / 32, DE / 32, NEXP), 256, 0, stream>>>(W2, W2t, DE, DM);
  router_kernel<<<512, 256, 0, stream>>>(x, Wr, topk, tkw, zP);
  scan_kernel<<<1, 512, 0, stream>>>((const int2*)topk, (const float2*)tkw, posk, wts, inv, kept);
  dispatch_kernel<<<NEXP * CAP, 256, 0, stream>>>(x, inv, buf);

  // GEMM1: (E, CAP, DM) x (E, DE, DM)^T -> (E, CAP, DE), ReLU. 10*16*8 = 1280 wgs.
  gemm8p<256, true><<<1280, 512, 0, stream>>>(buf, W1t, b1, h, CAP, DE, DM, 1280);
  // GEMM2: (E, CAP, DE) x (E, DM, DE)^T -> (E, CAP, DM). BM=128: 20*4*8 = 640 wgs.
  gemm8p<128, false><<<640, 512, 0, stream>>>(h, W2t, b2, eo, CAP, DM, DE, 640);

  combine_kernel<<<N_TOK, 256, 0, stream>>>(eo, posk, wts, topk, out);
  finalize_kernel<<<1, 64, 0, stream>>>(zP, kept, out + (size_t)N_TOK * DM);
}

// Round 4
// 655.914 us; speedup vs baseline: 1.2088x; 1.2088x over previous
//
#include <hip/hip_runtime.h>
#include <stdint.h>

#define N_TOK    8192
#define DM       1024      // D_MODEL
#define DE       4096      // D_EXPERT
#define NEXP     8
#define CAP      2560
#define AUX_CO   0.01f
#define Z_CO     0.001f

typedef __attribute__((ext_vector_type(4))) float f32x4;
typedef __attribute__((ext_vector_type(8))) __bf16 bf16x8;

static __device__ __forceinline__ unsigned short f2bf(float f) {
  union { float f; uint32_t u; } v; v.f = f;
  uint32_t r = 0x7fffu + ((v.u >> 16) & 1u);
  return (unsigned short)((v.u + r) >> 16);
}
static __device__ __forceinline__ float bf2f(unsigned short u) {
  union { uint32_t u; float f; } v; v.u = ((uint32_t)u) << 16;
  return v.f;
}

// ---------------- init: inv map = -1 ----------------
__global__ void init_inv(int* __restrict__ inv) {
  int i = blockIdx.x * 256 + threadIdx.x;
  if (i < NEXP * CAP) inv[i] = -1;
}

// ---------------- transpose + fp32->bf16: in (R,C) -> out (C,R), per expert z ----------------
__global__ __launch_bounds__(256) void transpose_to_bf16(
    const float* __restrict__ in, unsigned short* __restrict__ out, int R, int C)
{
  __shared__ float tile[32][33];
  const size_t eoff = (size_t)blockIdx.z * R * C;
  const int bx = blockIdx.x * 32, by = blockIdx.y * 32;
  const int tx = threadIdx.x & 31, ty = threadIdx.x >> 5;   // ty 0..7
#pragma unroll
  for (int i = 0; i < 4; ++i)
    tile[ty + 8*i][tx] = in[eoff + (size_t)(by + ty + 8*i) * C + bx + tx];
  __syncthreads();
#pragma unroll
  for (int i = 0; i < 4; ++i)
    out[eoff + (size_t)(bx + ty + 8*i) * R + by + tx] = f2bf(tile[tx][ty + 8*i]);
}

// ---------------- router ----------------
__global__ __launch_bounds__(256) void router_kernel(
    const float* __restrict__ x, const float* __restrict__ Wr,
    int* __restrict__ topk, float* __restrict__ tkw, float* __restrict__ zP)
{
  const int tid = threadIdx.x, lane = tid & 63, wave = tid >> 6;
  float zacc = 0.f;
  float pacc[NEXP];
#pragma unroll
  for (int e = 0; e < NEXP; ++e) pacc[e] = 0.f;

  for (int it = 0; it < 4; ++it) {
    const int t = blockIdx.x * 16 + it * 4 + wave;
    float acc[NEXP];
#pragma unroll
    for (int e = 0; e < NEXP; ++e) acc[e] = 0.f;
    const f32x4* x4 = (const f32x4*)(x + (size_t)t * DM);
#pragma unroll
    for (int i = 0; i < 4; ++i) {
      f32x4 xv = x4[i * 64 + lane];
#pragma unroll
      for (int j = 0; j < 4; ++j) {
        const float xs = xv[j];
        const float* wr = Wr + (size_t)((i * 64 + lane) * 4 + j) * NEXP;
#pragma unroll
        for (int e = 0; e < NEXP; ++e) acc[e] += xs * wr[e];
      }
    }
#pragma unroll
    for (int m = 32; m; m >>= 1)
#pragma unroll
      for (int e = 0; e < NEXP; ++e) acc[e] += __shfl_xor(acc[e], m);

    float mx = acc[0];
#pragma unroll
    for (int e = 1; e < NEXP; ++e) mx = fmaxf(mx, acc[e]);
    float p[NEXP], s = 0.f;
#pragma unroll
    for (int e = 0; e < NEXP; ++e) { p[e] = expf(acc[e] - mx); s += p[e]; }
    const float lse = mx + logf(s);
    zacc += lse * lse;
    const float inv_s = 1.f / s;
#pragma unroll
    for (int e = 0; e < NEXP; ++e) pacc[e] += p[e] * inv_s;

    int e0 = 0; float v0 = p[0];
#pragma unroll
    for (int e = 1; e < NEXP; ++e) if (p[e] > v0) { v0 = p[e]; e0 = e; }
    int e1 = -1; float v1 = -1.f;
#pragma unroll
    for (int e = 0; e < NEXP; ++e) if (e != e0 && p[e] > v1) { v1 = p[e]; e1 = e; }

    const float pr0 = v0 * inv_s, pr1 = v1 * inv_s;
    const float denom = fmaxf(pr0 + pr1, 1e-9f);
    if (lane == 0) {
      topk[2*t]   = e0; topk[2*t+1] = e1;
      tkw[2*t]    = pr0 / denom; tkw[2*t+1] = pr1 / denom;
    }
  }
  __shared__ float blk[4][9];
  if (lane == 0) {
    blk[wave][0] = zacc;
#pragma unroll
    for (int e = 0; e < NEXP; ++e) blk[wave][1 + e] = pacc[e];
  }
  __syncthreads();
  if (tid < 9)
    zP[blockIdx.x * 9 + tid] = blk[0][tid] + blk[1][tid] + blk[2][tid] + blk[3][tid];
}

// ---------------- scan: FCFS capacity positions, wave per expert ----------------
__global__ __launch_bounds__(512) void scan_kernel(
    const int2* __restrict__ topk, const float2* __restrict__ tkw,
    int* __restrict__ posk, float* __restrict__ wts,
    int* __restrict__ inv, int* __restrict__ kept)
{
  const int lane = threadIdx.x & 63;
  const int e = threadIdx.x >> 6;           // 8 waves = 8 experts
  int base = 0;
  const uint64_t below = (lane == 63) ? 0xFFFFFFFFFFFFFFFFull >> 1
                                      : ((1ull << lane) - 1ull);
  for (int i = 0; i < N_TOK / 64; ++i) {
    const int t = i * 64 + lane;
    const int2 ti = topk[t];
    const float2 w = tkw[t];
    const bool hit = (ti.x == e) || (ti.y == e);
    const uint64_t m = __ballot(hit);
    if (hit) {
      const int pos = base + (int)__popcll(m & below);
      const bool kp = pos < CAP;
      const int k = (ti.x == e) ? 0 : 1;
      posk[2*t + k] = kp ? pos : CAP;
      wts[2*t + k]  = kp ? ((k == 0) ? w.x : w.y) : 0.f;
      if (kp) inv[e * CAP + pos] = t;
    }
    base += (int)__popcll(m);
  }
  if (lane == 0) kept[e] = base < CAP ? base : CAP;
}

// ---------------- dispatch ----------------
__global__ __launch_bounds__(256) void dispatch_kernel(
    const float* __restrict__ x, const int* __restrict__ inv,
    unsigned short* __restrict__ buf)
{
  const int slot = blockIdx.x;
  const int t = inv[slot];
  ushort4 o;
  if (t >= 0) {
    const f32x4 v = ((const f32x4*)(x + (size_t)t * DM))[threadIdx.x];
    o.x = f2bf(v[0]); o.y = f2bf(v[1]); o.z = f2bf(v[2]); o.w = f2bf(v[3]);
  } else {
    o.x = 0; o.y = 0; o.z = 0; o.w = 0;
  }
  ((ushort4*)(buf + (size_t)slot * DM))[threadIdx.x] = o;
}

// ================ VARIANT A: m97 structure, 128x128 tile, 4 waves, BK=32, ==========
// ================ 16KB LDS single-buffer -> ~5 blocks resident/CU (TLP) ===========
template<bool RELU>
__global__ __launch_bounds__(256, 4) void gemmA(
    const unsigned short* __restrict__ A,   // (E, M, K) bf16
    const unsigned short* __restrict__ Bt,  // (E, N, K) bf16
    const float* __restrict__ bias,         // (E, N)
    unsigned short* __restrict__ C,         // (E, M, N) bf16
    const int* __restrict__ kept,
    int M, int N, int K, int n_base, int mt, int nt, int nwg)
{
  __shared__ __attribute__((aligned(16))) unsigned short As[128 * 32];
  __shared__ __attribute__((aligned(16))) unsigned short Bs[128 * 32];
  const int tid = threadIdx.x, lane = tid & 63, wave = tid >> 6;
  const int wr = wave >> 1, wc = wave & 1;
  const int frow = lane & 15, kgrp = lane >> 4;

  int wg = (int)blockIdx.x;                 // bijective XCD chunking (nwg%8==0)
  wg = (wg & 7) * (nwg >> 3) + (wg >> 3);
  const int ntpe = mt * nt;
  const int e = wg / ntpe, rr = wg % ntpe;
  const int m0 = (rr / nt) * 128;
  const int n0 = n_base + (rr % nt) * 128;
  if (m0 >= kept[e]) return;                // rows beyond capacity: output never read

  const unsigned short* Ae = A  + (size_t)e * M * K + (size_t)m0 * K;
  const unsigned short* Be = Bt + (size_t)e * N * K + (size_t)n0 * K;

  f32x4 acc[4][4];
#pragma unroll
  for (int m = 0; m < 4; ++m)
#pragma unroll
    for (int n = 0; n < 4; ++n) acc[m][n] = (f32x4){0.f, 0.f, 0.f, 0.f};

  for (int k0 = 0; k0 < K; k0 += 32) {
#pragma unroll
    for (int i = 0; i < 2; ++i) {
      const int row = i * 64 + (tid >> 2);
      const int col = ((tid & 3) ^ ((row >> 1) & 3)) * 8;   // pre-swizzled source
      const unsigned short* ga = Ae + (size_t)row * K + (k0 + col);
      const unsigned short* gb = Be + (size_t)row * K + (k0 + col);
      unsigned short* la = &As[i * 2048 + tid * 8];          // linear LDS dest
      unsigned short* lb = &Bs[i * 2048 + tid * 8];
      __builtin_amdgcn_global_load_lds((const __attribute__((address_space(1))) void*)ga,
                                       (__attribute__((address_space(3))) void*)la, 16, 0, 0);
      __builtin_amdgcn_global_load_lds((const __attribute__((address_space(1))) void*)gb,
                                       (__attribute__((address_space(3))) void*)lb, 16, 0, 0);
    }
    __syncthreads();   // drains vmcnt: staged data ready (m97 rhythm)
    bf16x8 af[4], bq[4];
#pragma unroll
    for (int m = 0; m < 4; ++m) {
      const int row = wr * 64 + m * 16 + frow;
      af[m] = *(const bf16x8*)&As[row * 32 + ((kgrp ^ ((row >> 1) & 3)) * 8)];
    }
#pragma unroll
    for (int n = 0; n < 4; ++n) {
      const int row = wc * 64 + n * 16 + frow;
      bq[n] = *(const bf16x8*)&Bs[row * 32 + ((kgrp ^ ((row >> 1) & 3)) * 8)];
    }
#pragma unroll
    for (int m = 0; m < 4; ++m)
#pragma unroll
      for (int n = 0; n < 4; ++n)
        acc[m][n] = __builtin_amdgcn_mfma_f32_16x16x32_bf16(af[m], bq[n], acc[m][n], 0, 0, 0);
    __syncthreads();   // reads done before next stage overwrites
  }

  const int r0 = m0 + wr * 64 + 4 * kgrp;
  const int c0 = n0 + wc * 64 + frow;
#pragma unroll
  for (int n = 0; n < 4; ++n) {
    const int cc = c0 + n * 16;
    const float bv = bias[(size_t)e * N + cc];
#pragma unroll
    for (int m = 0; m < 4; ++m) {
#pragma unroll
      for (int r = 0; r < 4; ++r) {
        float v = acc[m][n][r] + bv;
        if (RELU) v = fmaxf(v, 0.f);
        C[((size_t)e * M + (r0 + m * 16 + r)) * N + cc] = f2bf(v);
      }
    }
  }
}

// ================ VARIANT B: 256x256 tile, 8 waves, BK=64, 128KB dbuf, ============
// ================ 2-phase syncthreads (m230-V0 structure, 1 block/CU) =============
template<bool RELU>
__global__ __launch_bounds__(512, 2) void gemmB(
    const unsigned short* __restrict__ A,
    const unsigned short* __restrict__ Bt,
    const float* __restrict__ bias,
    unsigned short* __restrict__ C,
    const int* __restrict__ kept,
    int M, int N, int K, int n_base, int mt, int nt, int nwg)
{
  __shared__ __attribute__((aligned(16))) unsigned short As[2 * 256 * 64];
  __shared__ __attribute__((aligned(16))) unsigned short Bs[2 * 256 * 64];
  const int tid = threadIdx.x, lane = tid & 63, wave = tid >> 6;
  const int wr = wave >> 2, wc = wave & 3;            // 2m x 4n
  const int frow = lane & 15, kgrp = lane >> 4;

  int wg = (int)blockIdx.x;
  wg = (wg & 7) * (nwg >> 3) + (wg >> 3);
  const int ntpe = mt * nt;
  const int e = wg / ntpe, rr = wg % ntpe;
  const int m0 = (rr / nt) * 256;
  const int n0 = n_base + (rr % nt) * 256;
  if (m0 >= kept[e]) return;

  const unsigned short* Ae = A  + (size_t)e * M * K + (size_t)m0 * K;
  const unsigned short* Be = Bt + (size_t)e * N * K + (size_t)n0 * K;

  auto stage = [&](int buf, int k0) {
#pragma unroll
    for (int i = 0; i < 4; ++i) {
      const int row = i * 64 + (tid >> 3);
      const int cs = ((tid & 7) ^ (row & 7)) * 8;     // pre-swizzled source col
      const unsigned short* ga = Ae + (size_t)row * K + (k0 + cs);
      const unsigned short* gb = Be + (size_t)row * K + (k0 + cs);
      unsigned short* la = &As[buf * 16384 + i * 4096 + tid * 8];
      unsigned short* lb = &Bs[buf * 16384 + i * 4096 + tid * 8];
      __builtin_amdgcn_global_load_lds((const __attribute__((address_space(1))) void*)ga,
                                       (__attribute__((address_space(3))) void*)la, 16, 0, 0);
      __builtin_amdgcn_global_load_lds((const __attribute__((address_space(1))) void*)gb,
                                       (__attribute__((address_space(3))) void*)lb, 16, 0, 0);
    }
  };

  f32x4 acc[8][4];
#pragma unroll
  for (int m = 0; m < 8; ++m)
#pragma unroll
    for (int n = 0; n < 4; ++n) acc[m][n] = (f32x4){0.f, 0.f, 0.f, 0.f};

  const int nk = K >> 6;
  stage(0, 0);
  for (int t = 0; t < nk; ++t) {
    const int cur = t & 1;
    __syncthreads();                 // stage(t) landed; prior reads of buf cur^1 done
    if (t + 1 < nk) stage(cur ^ 1, (t + 1) * 64);
#pragma unroll
    for (int kk = 0; kk < 2; ++kk) {
      bf16x8 bq[4], af[8];
#pragma unroll
      for (int n = 0; n < 4; ++n) {
        const int row = wc * 64 + n * 16 + frow;
        const int slot = (kk * 4 + kgrp) ^ (row & 7);
        bq[n] = *(const bf16x8*)&Bs[cur * 16384 + row * 64 + slot * 8];
      }
#pragma unroll
      for (int m = 0; m < 8; ++m) {
        const int row = wr * 128 + m * 16 + frow;
        const int slot = (kk * 4 + kgrp) ^ (row & 7);
        af[m] = *(const bf16x8*)&As[cur * 16384 + row * 64 + slot * 8];
      }
      __builtin_amdgcn_s_setprio(1);
#pragma unroll
      for (int m = 0; m < 8; ++m)
#pragma unroll
        for (int n = 0; n < 4; ++n)
          acc[m][n] = __builtin_amdgcn_mfma_f32_16x16x32_bf16(af[m], bq[n], acc[m][n], 0, 0, 0);
      __builtin_amdgcn_s_setprio(0);
    }
  }

  const int r0 = m0 + wr * 128 + 4 * kgrp;
  const int c0 = n0 + wc * 64 + frow;
#pragma unroll
  for (int n = 0; n < 4; ++n) {
    const int cc = c0 + n * 16;
    const float bv = bias[(size_t)e * N + cc];
#pragma unroll
    for (int m = 0; m < 8; ++m) {
#pragma unroll
      for (int r = 0; r < 4; ++r) {
        float v = acc[m][n][r] + bv;
        if (RELU) v = fmaxf(v, 0.f);
        C[((size_t)e * M + (r0 + m * 16 + r)) * N + cc] = f2bf(v);
      }
    }
  }
}

// ---------------- combine ----------------
__global__ __launch_bounds__(256) void combine_kernel(
    const unsigned short* __restrict__ eo, const int* __restrict__ posk,
    const float* __restrict__ wts, const int* __restrict__ topk,
    float* __restrict__ out)
{
  const int t = blockIdx.x;
  const int e0 = topk[2*t], e1 = topk[2*t+1];
  int p0 = posk[2*t], p1 = posk[2*t+1];
  p0 = p0 < CAP - 1 ? p0 : CAP - 1;
  p1 = p1 < CAP - 1 ? p1 : CAP - 1;
  const float w0 = wts[2*t], w1 = wts[2*t+1];
  const ushort4 a = ((const ushort4*)(eo + ((size_t)e0 * CAP + p0) * DM))[threadIdx.x];
  const ushort4 b = ((const ushort4*)(eo + ((size_t)e1 * CAP + p1) * DM))[threadIdx.x];
  f32x4 o;
  o[0] = w0 * bf2f(a.x) + w1 * bf2f(b.x);
  o[1] = w0 * bf2f(a.y) + w1 * bf2f(b.y);
  o[2] = w0 * bf2f(a.z) + w1 * bf2f(b.z);
  o[3] = w0 * bf2f(a.w) + w1 * bf2f(b.w);
  ((f32x4*)(out + (size_t)t * DM))[threadIdx.x] = o;
}

// ---------------- finalize scalars ----------------
__global__ __launch_bounds__(64) void finalize_kernel(
    const float* __restrict__ zP, const int* __restrict__ kept,
    float* __restrict__ outs)
{
  const int lane = threadIdx.x;
  float v[9];
#pragma unroll
  for (int e = 0; e < 9; ++e) {
    float s = 0.f;
    for (int b = 0; b < 8; ++b) s += zP[(lane * 8 + b) * 9 + e];
    v[e] = s;
  }
#pragma unroll
  for (int m = 32; m; m >>= 1)
#pragma unroll
    for (int e = 0; e < 9; ++e) v[e] += __shfl_xor(v[e], m);
  if (lane == 0) {
    const float z = v[0] / (float)N_TOK;
    float total = 0.f;
    for (int e = 0; e < NEXP; ++e) total += (float)kept[e];
    total = fmaxf(total, 1.f);
    float aux = 0.f;
    for (int e = 0; e < NEXP; ++e)
      aux += ((float)kept[e] / total) * (v[1 + e] / (float)N_TOK);
    aux *= (float)NEXP;
    outs[0] = aux;
    outs[1] = z;
    outs[2] = AUX_CO * aux + Z_CO * z;
  }
}

extern "C" void kernel_launch(void* const* d_in, const int* in_sizes, int n_in,
                              void* d_out, int out_size, void* d_ws, size_t ws_size,
                              hipStream_t stream)
{
  const float* x  = (const float*)d_in[0];
  const float* Wr = (const float*)d_in[1];
  const float* W1 = (const float*)d_in[2];
  const float* b1 = (const float*)d_in[3];
  const float* W2 = (const float*)d_in[4];
  const float* b2 = (const float*)d_in[5];
  float* out = (float*)d_out;

  char* p = (char*)d_ws;
  auto alloc = [&](size_t bytes) {
    char* q = p; p += (bytes + 255) & ~(size_t)255; return q;
  };
  unsigned short* W1t = (unsigned short*)alloc((size_t)NEXP * DM * DE * 2);   // (E, DE, DM)
  unsigned short* W2t = (unsigned short*)alloc((size_t)NEXP * DM * DE * 2);   // (E, DM, DE)
  unsigned short* buf = (unsigned short*)alloc((size_t)NEXP * CAP * DM * 2);  // (E, cap, DM)
  unsigned short* h   = (unsigned short*)alloc((size_t)NEXP * CAP * DE * 2);  // (E, cap, DE)
  unsigned short* eo  = (unsigned short*)alloc((size_t)NEXP * CAP * DM * 2);  // (E, cap, DM)
  int*   topk = (int*)alloc((size_t)N_TOK * 2 * 4);
  float* tkw  = (float*)alloc((size_t)N_TOK * 2 * 4);
  int*   posk = (int*)alloc((size_t)N_TOK * 2 * 4);
  float* wts  = (float*)alloc((size_t)N_TOK * 2 * 4);
  int*   inv  = (int*)alloc((size_t)NEXP * CAP * 4);
  int*   kept = (int*)alloc((size_t)NEXP * 4);
  float* zP   = (float*)alloc((size_t)512 * 9 * 4);

  init_inv<<<(NEXP * CAP + 255) / 256, 256, 0, stream>>>(inv);
  transpose_to_bf16<<<dim3(DE / 32, DM / 32, NEXP), 256, 0, stream>>>(W1, W1t, DM, DE);
  transpose_to_bf16<<<dim3(DM / 32, DE / 32, NEXP), 256, 0, stream>>>(W2, W2t, DE, DM);
  router_kernel<<<512, 256, 0, stream>>>(x, Wr, topk, tkw, zP);
  scan_kernel<<<1, 512, 0, stream>>>((const int2*)topk, (const float2*)tkw, posk, wts, inv, kept);
  dispatch_kernel<<<NEXP * CAP, 256, 0, stream>>>(x, inv, buf);

  // ===== GEMM1 A/B split by n-range (same work per half: 85.9 GFLOP each) =====
  // half A: n in [0,2048): 20m x 16n x 8e = 2560 blocks, 16KB LDS (high residency)
  gemmA<true><<<2560, 256, 0, stream>>>(buf, W1t, b1, h, kept, CAP, DE, DM,
                                        0, 20, 16, 2560);
  // half B: n in [2048,4096): 10m x 8n x 8e = 640 blocks, 128KB LDS (big tile)
  gemmB<true><<<640, 512, 0, stream>>>(buf, W1t, b1, h, kept, CAP, DE, DM,
                                       2048, 10, 8, 640);

  // ===== GEMM2: structure A over full N (control) =====
  gemmA<false><<<1280, 256, 0, stream>>>(h, W2t, b2, eo, kept, CAP, DM, DE,
                                         0, 20, 8, 1280);

  combine_kernel<<<N_TOK, 256, 0, stream>>>(eo, posk, wts, topk, out);
  finalize_kernel<<<1, 64, 0, stream>>>(zP, kept, out + (size_t)N_TOK * DM);
}